// Round 2
// baseline (5930.700 us; speedup 1.0000x reference)
//
#include <hip/hip_runtime.h>
#include <cstdint>
#include <cstddef>

#define SEQ   256
#define INP   4
#define BOND  128
#define BATCH 2048
#define MATSZ (BOND*BOND)

typedef __bf16 bf16x8 __attribute__((ext_vector_type(8)));
typedef float  f32x4  __attribute__((ext_vector_type(4)));

// ---- workspace layout (bytes) ----
static constexpr size_t SZ_MAT   = (size_t)SEQ*INP*MATSZ*2;   // 32 MiB each
static constexpr size_t OFF_ABF  = 0;
static constexpr size_t OFF_ATBF = OFF_ABF + SZ_MAT;
static constexpr size_t OFF_BHI  = OFF_ATBF + SZ_MAT;
static constexpr size_t OFF_BLO  = OFF_BHI + SZ_MAT;
static constexpr size_t SZ_MWS   = 2ull*2*MATSZ*2;            // 2 chains * 2 bufs * bf16
static constexpr size_t SZ_FLAGS = 16384;
static constexpr size_t SZ_TAIL  = SZ_MWS + SZ_FLAGS + (size_t)BATCH*4 + 64;

static __device__ __forceinline__ unsigned short f2bf(float f) {
    union { float f; uint32_t u; } v; v.f = f;
    uint32_t r = (v.u + 0x7FFFu + ((v.u >> 16) & 1u)) >> 16;   // RNE
    return (unsigned short)r;
}
static __device__ __forceinline__ float bf2f(unsigned short b) {
    union { uint32_t u; float f; } v; v.u = ((uint32_t)b) << 16;
    return v.f;
}
static __device__ __forceinline__ f32x4 mfma16(bf16x8 a, bf16x8 b, f32x4 c) {
    return __builtin_amdgcn_mfma_f32_16x16x32_bf16(a, b, c, 0, 0, 0);
}

// ---------------- convert: fp32 core -> bf16 A, bf16 A^T, bf16 hi/lo of (A - I) ----------------
__global__ void convert_kernel(const float* __restrict__ core,
                               unsigned short* __restrict__ abf,
                               unsigned short* __restrict__ atbf,
                               unsigned short* __restrict__ bhi,
                               unsigned short* __restrict__ blo,
                               int use_blo) {
    __shared__ unsigned short tile[BOND][BOND + 2];
    const int mat = blockIdx.x;                       // 0..1023  (t*4+v)
    const float* src = core + (size_t)mat * MATSZ;
    unsigned short* dA = abf  + (size_t)mat * MATSZ;
    unsigned short* dT = atbf + (size_t)mat * MATSZ;
    unsigned short* dH = bhi  + (size_t)mat * MATSZ;
    unsigned short* dL = blo  + (size_t)mat * MATSZ;
    const int tid = threadIdx.x;
    for (int j = 0; j < 16; ++j) {
        int lin4 = (tid + j * 256) * 4;
        float4 f = *(const float4*)(src + lin4);
        int r = lin4 >> 7, c = lin4 & 127;
        unsigned short a0=f2bf(f.x), a1=f2bf(f.y), a2=f2bf(f.z), a3=f2bf(f.w);
        *(ushort4*)(dA + lin4) = make_ushort4(a0,a1,a2,a3);
        tile[r][c]=a0; tile[r][c+1]=a1; tile[r][c+2]=a2; tile[r][c+3]=a3;
        // delta form: B = A - I (branchless diagonal subtract)
        float b0 = f.x - ((r == c    ) ? 1.0f : 0.0f);
        float b1 = f.y - ((r == c + 1) ? 1.0f : 0.0f);
        float b2 = f.z - ((r == c + 2) ? 1.0f : 0.0f);
        float b3 = f.w - ((r == c + 3) ? 1.0f : 0.0f);
        unsigned short h0=f2bf(b0), h1=f2bf(b1), h2=f2bf(b2), h3=f2bf(b3);
        *(ushort4*)(dH + lin4) = make_ushort4(h0,h1,h2,h3);
        if (use_blo) {
            *(ushort4*)(dL + lin4) = make_ushort4(
                f2bf(b0 - bf2f(h0)), f2bf(b1 - bf2f(h1)),
                f2bf(b2 - bf2f(h2)), f2bf(b3 - bf2f(h3)));
        }
    }
    __syncthreads();
    for (int j = 0; j < 16; ++j) {
        int lin4 = (tid + j * 256) * 4;                // linear index in AT (c*128 + r)
        int co = lin4 >> 7, r0 = lin4 & 127;
        *(ushort4*)(dT + lin4) = make_ushort4(tile[r0][co], tile[r0+1][co],
                                              tile[r0+2][co], tile[r0+3][co]);
    }
}

// ---------------- main kernel: blocks 0..15 = Z chains (unchanged), 16..79 = amplitude ----------------
struct ZSm {
    unsigned short M[BOND][136];
    unsigned short Ti[16][136];
    float vec[BOND];
    float red[256];
};
struct ASm {
    float hf[32][132];              // fp32 h state
    unsigned short hhi[32][136];    // bf16 hi of h
    unsigned short hlo[32][136];    // bf16 lo of h
    float logn[32];
    float partial[4][32];
    float sinv[32];
    int   tok[32];
    float ev[BOND];
};
union SmU { ZSm z; ASm a; };

template<int USE_BLO>
__global__ __launch_bounds__(256) void main_kernel(
        const int*   __restrict__ xdata,
        const float* __restrict__ edge,
        const unsigned short* __restrict__ abf,
        const unsigned short* __restrict__ atbf,
        const unsigned short* __restrict__ bhi,
        const unsigned short* __restrict__ blo,
        unsigned short* __restrict__ mws,
        unsigned int*   __restrict__ flags,
        float* __restrict__ logamp,
        float* __restrict__ logzp) {
    __shared__ SmU sm;
    const int tid = threadIdx.x;
    const int l   = tid & 63;
    const int w   = tid >> 6;          // wave 0..3
    const int lr  = l & 15;
    const int lq  = l >> 4;

    if (blockIdx.x < 16) {
        // ================= Z chains (identical to previous round) =================
        const int bz    = blockIdx.x;
        const int chain = bz >> 3;     // 0 = fwd (alpha), 1 = bwd (omega, via A^T)
        const int k     = bz & 7;      // slice index, rows R..R+15
        const int R     = k * 16;
        unsigned short* mbase = mws + (size_t)chain * 2 * MATSZ;
        unsigned int*   fl    = flags + (size_t)chain * 129 * 8;
        const unsigned short* Abase = (chain == 0) ? abf : atbf;

        if (tid < BOND) sm.z.vec[tid] = edge[(chain == 0 ? 0 : BOND) + tid];
        __syncthreads();
        for (int j = 0; j < 8; ++j) {
            int idx = tid * 8 + j;
            int rl = idx >> 7, c = idx & 127;
            mbase[(size_t)(R + rl) * BOND + c] = f2bf(sm.z.vec[R + rl] * sm.z.vec[c]);
        }
        __builtin_amdgcn_fence(__ATOMIC_RELEASE, "agent");
        __syncthreads();
        if (tid == 0)
            __hip_atomic_store(&fl[k], 1u, __ATOMIC_RELEASE, __HIP_MEMORY_SCOPE_AGENT);
        if (l == 0)
            for (int kk = 0; kk < 8; ++kk)
                while (__hip_atomic_load(&fl[kk], __ATOMIC_ACQUIRE, __HIP_MEMORY_SCOPE_AGENT) == 0u)
                    __builtin_amdgcn_s_sleep(1);
        __syncthreads();
        __builtin_amdgcn_fence(__ATOMIC_ACQUIRE, "agent");
        for (int j = 0; j < 8; ++j) {
            int chunk = tid + j * 256;
            int r = chunk >> 4, cc = (chunk & 15) * 8;
            *(bf16x8*)&sm.z.M[r][cc] = *(const bf16x8*)(mbase + (size_t)r * BOND + cc);
        }
        __syncthreads();

        for (int s = 1; s <= 128; ++s) {
            const int tstep = (chain == 0) ? (s - 1) : (SEQ - s);
            const unsigned short* As = Abase + (size_t)tstep * INP * MATSZ;
            f32x4 accM[2] = {};
            for (int i = 0; i < 4; ++i) {
                const unsigned short* Ai = As + (size_t)i * MATSZ;
                f32x4 accT[2] = {};
#pragma unroll
                for (int kk = 0; kk < 4; ++kk) {
                    bf16x8 af = *(const bf16x8*)(Ai + (size_t)(R + lr) * BOND + kk * 32 + lq * 8);
#pragma unroll
                    for (int nt = 0; nt < 2; ++nt) {
                        int cti = 2 * w + nt;
                        bf16x8 bfM = *(const bf16x8*)&sm.z.M[cti * 16 + lr][kk * 32 + lq * 8];
                        accT[nt] = mfma16(af, bfM, accT[nt]);
                    }
                }
                __syncthreads();
#pragma unroll
                for (int nt = 0; nt < 2; ++nt)
#pragma unroll
                    for (int r = 0; r < 4; ++r)
                        sm.z.Ti[lq * 4 + r][(2 * w + nt) * 16 + lr] = f2bf(accT[nt][r]);
                __syncthreads();
#pragma unroll
                for (int kk = 0; kk < 4; ++kk) {
                    bf16x8 tf = *(const bf16x8*)&sm.z.Ti[lr][kk * 32 + lq * 8];
#pragma unroll
                    for (int nt = 0; nt < 2; ++nt) {
                        bf16x8 ba = *(const bf16x8*)(Ai + (size_t)((2 * w + nt) * 16 + lr) * BOND + kk * 32 + lq * 8);
                        accM[nt] = mfma16(tf, ba, accM[nt]);
                    }
                }
            }
            const int nb = s & 1;
            unsigned short* outb = mbase + (size_t)nb * MATSZ;
#pragma unroll
            for (int nt = 0; nt < 2; ++nt)
#pragma unroll
                for (int r = 0; r < 4; ++r)
                    outb[(size_t)(R + lq * 4 + r) * BOND + (2 * w + nt) * 16 + lr] =
                        f2bf(accM[nt][r] * 0.25f);
            __builtin_amdgcn_fence(__ATOMIC_RELEASE, "agent");
            __syncthreads();
            if (tid == 0)
                __hip_atomic_store(&fl[s * 8 + k], 1u, __ATOMIC_RELEASE, __HIP_MEMORY_SCOPE_AGENT);
            if (l == 0)
                for (int kk = 0; kk < 8; ++kk)
                    while (__hip_atomic_load(&fl[s * 8 + kk], __ATOMIC_ACQUIRE, __HIP_MEMORY_SCOPE_AGENT) == 0u)
                        __builtin_amdgcn_s_sleep(1);
            __syncthreads();
            __builtin_amdgcn_fence(__ATOMIC_ACQUIRE, "agent");
            for (int j = 0; j < 8; ++j) {
                int chunk = tid + j * 256;
                int r = chunk >> 4, cc = (chunk & 15) * 8;
                *(bf16x8*)&sm.z.M[r][cc] = *(const bf16x8*)(outb + (size_t)r * BOND + cc);
            }
            __syncthreads();
        }

        if (chain == 0 && k == 0) {
            unsigned int* fl1 = flags + 129 * 8;
            if (l == 0)
                for (int kk = 0; kk < 8; ++kk)
                    while (__hip_atomic_load(&fl1[128 * 8 + kk], __ATOMIC_ACQUIRE, __HIP_MEMORY_SCOPE_AGENT) == 0u)
                        __builtin_amdgcn_s_sleep(1);
            __syncthreads();
            __builtin_amdgcn_fence(__ATOMIC_ACQUIRE, "agent");
            const unsigned short* Sf = mws;
            const unsigned short* Rb = mws + 2 * MATSZ;
            float part = 0.f;
            for (int j = 0; j < 64; ++j) {
                int idx = tid + j * 256;
                part += bf2f(Sf[idx]) * bf2f(Rb[idx]);
            }
            sm.z.red[tid] = part;
            __syncthreads();
            for (int off = 128; off > 0; off >>= 1) {
                if (tid < off) sm.z.red[tid] += sm.z.red[tid + off];
                __syncthreads();
            }
            if (tid == 0)
                logzp[0] = logf(sm.z.red[0]) + 256.0f * 1.3862943611198906f;
        }
    } else {
        // ================= amplitude scan, delta form: h' = h + B[tok] h =================
        const int b0 = (blockIdx.x - 16) * 32;
        if (tid < BOND) sm.a.ev[tid] = edge[tid];        // alpha
        if (tid < 32)  sm.a.logn[tid] = 0.f;
        __syncthreads();
        for (int j = 0; j < 16; ++j) {
            int idx = tid + j * 256;                     // 32 cols * 128 rows
            int c = idx >> 7, r = idx & 127;
            float v = sm.a.ev[r];
            unsigned short h = f2bf(v);
            sm.a.hf[c][r]  = v;
            sm.a.hhi[c][r] = h;
            sm.a.hlo[c][r] = f2bf(v - bf2f(h));
        }
        __syncthreads();

        for (int t = 0; t < SEQ; ++t) {
            if (tid < 32) sm.a.tok[tid] = xdata[(size_t)t * BATCH + b0 + tid];
            __syncthreads();
            const unsigned short* Bh = bhi + (size_t)t * INP * MATSZ;
            const unsigned short* Bl = blo + (size_t)t * INP * MATSZ;
            f32x4 acc[4][2][2] = {};   // [token v][row-tile mi][col-tile ct]
#pragma unroll
            for (int kk = 0; kk < 4; ++kk) {
                bf16x8 hh[2], hl[2];
#pragma unroll
                for (int ct = 0; ct < 2; ++ct) {
                    hh[ct] = *(const bf16x8*)&sm.a.hhi[ct * 16 + lr][kk * 32 + lq * 8];
                    hl[ct] = *(const bf16x8*)&sm.a.hlo[ct * 16 + lr][kk * 32 + lq * 8];
                }
#pragma unroll
                for (int v = 0; v < 4; ++v)
#pragma unroll
                    for (int mi = 0; mi < 2; ++mi) {
                        const size_t ro = (size_t)v * MATSZ + (size_t)(w * 32 + mi * 16 + lr) * BOND + kk * 32 + lq * 8;
                        bf16x8 bh = *(const bf16x8*)(Bh + ro);
#pragma unroll
                        for (int ct = 0; ct < 2; ++ct) {
                            acc[v][mi][ct] = mfma16(bh, hh[ct], acc[v][mi][ct]);
                            acc[v][mi][ct] = mfma16(bh, hl[ct], acc[v][mi][ct]);
                        }
                        if (USE_BLO) {
                            bf16x8 bl = *(const bf16x8*)(Bl + ro);
#pragma unroll
                            for (int ct = 0; ct < 2; ++ct)
                                acc[v][mi][ct] = mfma16(bl, hh[ct], acc[v][mi][ct]);
                        }
                    }
            }
            // select token delta, add to fp32 h, accumulate norms
            f32x4 hn[2][2];
#pragma unroll
            for (int ct = 0; ct < 2; ++ct) {
                int tok = sm.a.tok[ct * 16 + lr];
                float ss = 0.f;
#pragma unroll
                for (int mi = 0; mi < 2; ++mi) {
                    f32x4 d = acc[0][mi][ct];
                    d = (tok == 1) ? acc[1][mi][ct] : d;
                    d = (tok == 2) ? acc[2][mi][ct] : d;
                    d = (tok == 3) ? acc[3][mi][ct] : d;
                    f32x4 ho = *(const f32x4*)&sm.a.hf[ct * 16 + lr][w * 32 + mi * 16 + lq * 4];
                    f32x4 h2 = ho + d;
                    hn[ct][mi] = h2;
#pragma unroll
                    for (int r = 0; r < 4; ++r) ss += h2[r] * h2[r];
                }
                ss += __shfl_xor(ss, 16);
                ss += __shfl_xor(ss, 32);
                if (lq == 0) sm.a.partial[w][ct * 16 + lr] = ss;
            }
            __syncthreads();
            if (tid < 32) {
                float s2 = sm.a.partial[0][tid] + sm.a.partial[1][tid]
                         + sm.a.partial[2][tid] + sm.a.partial[3][tid];
                sm.a.sinv[tid] = rsqrtf(s2);
                sm.a.logn[tid] += 0.5f * logf(s2);
            }
            __syncthreads();
#pragma unroll
            for (int ct = 0; ct < 2; ++ct) {
                float si = sm.a.sinv[ct * 16 + lr];
#pragma unroll
                for (int mi = 0; mi < 2; ++mi) {
                    f32x4 h2 = hn[ct][mi] * si;
                    *(f32x4*)&sm.a.hf[ct * 16 + lr][w * 32 + mi * 16 + lq * 4] = h2;
                    unsigned short q0 = f2bf(h2[0]), q1 = f2bf(h2[1]),
                                   q2 = f2bf(h2[2]), q3 = f2bf(h2[3]);
                    *(ushort4*)&sm.a.hhi[ct * 16 + lr][w * 32 + mi * 16 + lq * 4] =
                        make_ushort4(q0, q1, q2, q3);
                    *(ushort4*)&sm.a.hlo[ct * 16 + lr][w * 32 + mi * 16 + lq * 4] =
                        make_ushort4(f2bf(h2[0] - bf2f(q0)), f2bf(h2[1] - bf2f(q1)),
                                     f2bf(h2[2] - bf2f(q2)), f2bf(h2[3] - bf2f(q3)));
                }
            }
            __syncthreads();
        }
        if (tid < BOND) sm.a.ev[tid] = edge[BOND + tid];  // omega
        __syncthreads();
        if (tid < 32) {
            float dot = 0.f;
            for (int r = 0; r < BOND; ++r) dot += sm.a.hf[tid][r] * sm.a.ev[r];
            logamp[b0 + tid] = 2.f * (logf(fabsf(dot)) + sm.a.logn[tid]);
        }
    }
}

__global__ void fin_kernel(const float* __restrict__ logamp,
                           const float* __restrict__ logzp,
                           float* __restrict__ out) {
    int b = blockIdx.x * 256 + threadIdx.x;
    if (b < BATCH) out[b] = logamp[b] - logzp[0];
}

extern "C" void kernel_launch(void* const* d_in, const int* in_sizes, int n_in,
                              void* d_out, int out_size, void* d_ws, size_t ws_size,
                              hipStream_t stream) {
    const int*   xdata = (const int*)d_in[0];
    const float* core  = (const float*)d_in[1];
    const float* edge  = (const float*)d_in[2];
    float* out = (float*)d_out;
    char* ws = (char*)d_ws;

    const size_t need_full  = OFF_BLO + SZ_MAT + SZ_TAIL;
    const size_t need_noblo = OFF_BLO + SZ_TAIL;
    const int use_blo = (ws_size >= need_full) ? 1 : 0;
    if (!use_blo && ws_size < need_noblo) return;

    unsigned short* abf  = (unsigned short*)(ws + OFF_ABF);
    unsigned short* atbf = (unsigned short*)(ws + OFF_ATBF);
    unsigned short* bhi  = (unsigned short*)(ws + OFF_BHI);
    unsigned short* blo  = (unsigned short*)(ws + (use_blo ? OFF_BLO : OFF_BHI));
    const size_t tail = use_blo ? (OFF_BLO + SZ_MAT) : OFF_BLO;
    unsigned short* mws  = (unsigned short*)(ws + tail);
    unsigned int* flags  = (unsigned int*)(ws + tail + SZ_MWS);
    float* logamp = (float*)(ws + tail + SZ_MWS + SZ_FLAGS);
    float* logzp  = (float*)(ws + tail + SZ_MWS + SZ_FLAGS + (size_t)BATCH*4);

    hipMemsetAsync(flags, 0, SZ_FLAGS, stream);
    convert_kernel<<<SEQ * INP, 256, 0, stream>>>(core, abf, atbf, bhi, blo, use_blo);
    if (use_blo)
        main_kernel<1><<<80, 256, 0, stream>>>(xdata, edge, abf, atbf, bhi, blo, mws, flags, logamp, logzp);
    else
        main_kernel<0><<<80, 256, 0, stream>>>(xdata, edge, abf, atbf, bhi, blo, mws, flags, logamp, logzp);
    fin_kernel<<<(BATCH + 255) / 256, 256, 0, stream>>>(logamp, logzp, out);
}

// Round 3
// 5732.426 us; speedup vs baseline: 1.0346x; 1.0346x over previous
//
#include <hip/hip_runtime.h>
#include <cstdint>
#include <cstddef>

#define SEQ   256
#define INP   4
#define BOND  128
#define BATCH 2048
#define MATSZ (BOND*BOND)

typedef __bf16 bf16x8 __attribute__((ext_vector_type(8)));
typedef float  f32x4  __attribute__((ext_vector_type(4)));

// ---- workspace layout (bytes) ----
static constexpr size_t SZ_MAT   = (size_t)SEQ*INP*MATSZ*2;   // 32 MiB each
static constexpr size_t OFF_ABF  = 0;
static constexpr size_t OFF_ATBF = OFF_ABF + SZ_MAT;
static constexpr size_t OFF_BHI  = OFF_ATBF + SZ_MAT;
static constexpr size_t OFF_BLO  = OFF_BHI + SZ_MAT;
static constexpr size_t SZ_MWS   = 2ull*MATSZ*2;              // 2 chains * final M (bf16)
static constexpr size_t SZ_TAIL  = SZ_MWS + (size_t)BATCH*4 + 64;

static __device__ __forceinline__ unsigned short f2bf(float f) {
    union { float f; uint32_t u; } v; v.f = f;
    uint32_t r = (v.u + 0x7FFFu + ((v.u >> 16) & 1u)) >> 16;   // RNE
    return (unsigned short)r;
}
static __device__ __forceinline__ float bf2f(unsigned short b) {
    union { uint32_t u; float f; } v; v.u = ((uint32_t)b) << 16;
    return v.f;
}
static __device__ __forceinline__ f32x4 mfma16(bf16x8 a, bf16x8 b, f32x4 c) {
    return __builtin_amdgcn_mfma_f32_16x16x32_bf16(a, b, c, 0, 0, 0);
}

// ---------------- convert: fp32 core -> bf16 A, bf16 A^T, bf16 hi/lo of (A - I) ----------------
__global__ void convert_kernel(const float* __restrict__ core,
                               unsigned short* __restrict__ abf,
                               unsigned short* __restrict__ atbf,
                               unsigned short* __restrict__ bhi,
                               unsigned short* __restrict__ blo,
                               int use_blo) {
    __shared__ unsigned short tile[BOND][BOND + 2];
    const int mat = blockIdx.x;                       // 0..1023  (t*4+v)
    const float* src = core + (size_t)mat * MATSZ;
    unsigned short* dA = abf  + (size_t)mat * MATSZ;
    unsigned short* dT = atbf + (size_t)mat * MATSZ;
    unsigned short* dH = bhi  + (size_t)mat * MATSZ;
    unsigned short* dL = blo  + (size_t)mat * MATSZ;
    const int tid = threadIdx.x;
    for (int j = 0; j < 16; ++j) {
        int lin4 = (tid + j * 256) * 4;
        float4 f = *(const float4*)(src + lin4);
        int r = lin4 >> 7, c = lin4 & 127;
        unsigned short a0=f2bf(f.x), a1=f2bf(f.y), a2=f2bf(f.z), a3=f2bf(f.w);
        *(ushort4*)(dA + lin4) = make_ushort4(a0,a1,a2,a3);
        tile[r][c]=a0; tile[r][c+1]=a1; tile[r][c+2]=a2; tile[r][c+3]=a3;
        float b0 = f.x - ((r == c    ) ? 1.0f : 0.0f);
        float b1 = f.y - ((r == c + 1) ? 1.0f : 0.0f);
        float b2 = f.z - ((r == c + 2) ? 1.0f : 0.0f);
        float b3 = f.w - ((r == c + 3) ? 1.0f : 0.0f);
        unsigned short h0=f2bf(b0), h1=f2bf(b1), h2=f2bf(b2), h3=f2bf(b3);
        *(ushort4*)(dH + lin4) = make_ushort4(h0,h1,h2,h3);
        if (use_blo) {
            *(ushort4*)(dL + lin4) = make_ushort4(
                f2bf(b0 - bf2f(h0)), f2bf(b1 - bf2f(h1)),
                f2bf(b2 - bf2f(h2)), f2bf(b3 - bf2f(h3)));
        }
    }
    __syncthreads();
    for (int j = 0; j < 16; ++j) {
        int lin4 = (tid + j * 256) * 4;
        int co = lin4 >> 7, r0 = lin4 & 127;
        *(ushort4*)(dT + lin4) = make_ushort4(tile[r0][co], tile[r0+1][co],
                                              tile[r0+2][co], tile[r0+3][co]);
    }
}

// ---------------- main kernel: blocks 0..1 = Z chains (single-block scans), 2..65 = amplitude ----------------
struct ZSm {
    unsigned short M[BOND][136];    // current density matrix (bf16, padded)
    unsigned short Ti[BOND][136];   // intermediate T = A_i * M
    float vec[BOND];
};
struct ASm {
    int   toks[SEQ * 32];           // prefetched tokens for this block's 32 columns
    float hf[32][132];              // fp32 h state (col-major: [col][dim])
    unsigned short hhi[32][136];    // bf16 hi of h
    unsigned short hlo[32][136];    // bf16 lo of h
    float ev[BOND];
    float partial[8][32];
    float sinv[32];
    float logn[32];
};
union SmU { ZSm z; ASm a; };

template<int USE_BLO>
__global__ __launch_bounds__(512) void main_kernel(
        const int*   __restrict__ xdata,
        const float* __restrict__ edge,
        const unsigned short* __restrict__ abf,
        const unsigned short* __restrict__ atbf,
        const unsigned short* __restrict__ bhi,
        const unsigned short* __restrict__ blo,
        unsigned short* __restrict__ mws,
        float* __restrict__ logamp) {
    __shared__ SmU sm;
    const int tid = threadIdx.x;
    const int l   = tid & 63;
    const int w   = tid >> 6;          // wave 0..7
    const int lr  = l & 15;
    const int lq  = l >> 4;

    if (blockIdx.x < 2) {
        // ================= Z chain: whole scan in ONE block, LDS-resident =================
        const int chain = blockIdx.x;                  // 0 = fwd (alpha), 1 = bwd (omega, A^T)
        const unsigned short* Abase = chain ? atbf : abf;
        const int R = w * 16;                          // wave's 16-row slice

        if (tid < BOND) sm.z.vec[tid] = edge[chain * BOND + tid];
        __syncthreads();
        for (int j = 0; j < 32; ++j) {
            int idx = tid + j * 512;                   // 16384 elements
            int r = idx >> 7, c = idx & 127;
            sm.z.M[r][c] = f2bf(sm.z.vec[r] * sm.z.vec[c]);
        }
        __syncthreads();

        for (int s = 1; s <= 128; ++s) {
            const int tstep = (chain == 0) ? (s - 1) : (SEQ - s);
            const unsigned short* As = Abase + (size_t)tstep * INP * MATSZ;
            f32x4 accM[8] = {};
            for (int i = 0; i < 4; ++i) {
                const unsigned short* Ai = As + (size_t)i * MATSZ;
                // phase 1: T rows [R,R+16) = A_i[R..][:] * M   (M symmetric -> row B-frags)
                f32x4 accT[8] = {};
#pragma unroll
                for (int kk = 0; kk < 4; ++kk) {
                    bf16x8 af = *(const bf16x8*)(Ai + (size_t)(R + lr) * BOND + kk * 32 + lq * 8);
#pragma unroll
                    for (int nt = 0; nt < 8; ++nt)
                        accT[nt] = mfma16(af, *(const bf16x8*)&sm.z.M[nt * 16 + lr][kk * 32 + lq * 8], accT[nt]);
                }
                __syncthreads();       // prev phase-2 done reading Ti
#pragma unroll
                for (int nt = 0; nt < 8; ++nt)
#pragma unroll
                    for (int r = 0; r < 4; ++r)
                        sm.z.Ti[R + lq * 4 + r][nt * 16 + lr] = f2bf(accT[nt][r]);
                __syncthreads();
                // phase 2: accM += T[R..][:] * A_i^T  (B[k=c][n=d] = A_i[d][c], row-contiguous)
#pragma unroll
                for (int kk = 0; kk < 4; ++kk) {
                    bf16x8 tf = *(const bf16x8*)&sm.z.Ti[R + lr][kk * 32 + lq * 8];
#pragma unroll
                    for (int nt = 0; nt < 8; ++nt) {
                        bf16x8 ba = *(const bf16x8*)(Ai + (size_t)(nt * 16 + lr) * BOND + kk * 32 + lq * 8);
                        accM[nt] = mfma16(tf, ba, accM[nt]);
                    }
                }
            }
            // safe: all phase-1 M reads completed before i=3's post-Ti-write sync
#pragma unroll
            for (int nt = 0; nt < 8; ++nt)
#pragma unroll
                for (int r = 0; r < 4; ++r)
                    sm.z.M[R + lq * 4 + r][nt * 16 + lr] = f2bf(accM[nt][r] * 0.25f);
            __syncthreads();
        }
        // publish final M for this chain
        unsigned short* outb = mws + (size_t)chain * MATSZ;
        for (int j = 0; j < 4; ++j) {
            int chunk = tid + j * 512;                 // 2048 chunks of 8
            int r = chunk >> 4, cc = (chunk & 15) * 8;
            *(bf16x8*)(outb + (size_t)r * BOND + cc) = *(const bf16x8*)&sm.z.M[r][cc];
        }
    } else {
        // ================= amplitude scan, delta form: h' = h + B[tok] h =================
        const int b0 = (blockIdx.x - 2) * 32;
        for (int j = 0; j < 16; ++j) {
            int idx = tid + j * 512;                   // 8192 tokens
            int t = idx >> 5, c = idx & 31;
            sm.a.toks[idx] = xdata[(size_t)t * BATCH + b0 + c];
        }
        if (tid < BOND) sm.a.ev[tid] = edge[tid];      // alpha
        if (tid < 32)  sm.a.logn[tid] = 0.f;
        __syncthreads();
        for (int j = 0; j < 8; ++j) {
            int idx = tid + j * 512;                   // 32 cols * 128 dims
            int c = idx >> 7, r = idx & 127;
            float v = sm.a.ev[r];
            unsigned short hh = f2bf(v);
            sm.a.hf[c][r]  = v;
            sm.a.hhi[c][r] = hh;
            sm.a.hlo[c][r] = f2bf(v - bf2f(hh));
        }
        __syncthreads();

        for (int t = 0; t < SEQ; ++t) {
            const unsigned short* Bh = bhi + (size_t)t * INP * MATSZ;
            const unsigned short* Bl = blo + (size_t)t * INP * MATSZ;
            f32x4 acc[4][2] = {};                      // [token][col-tile]
#pragma unroll
            for (int kk = 0; kk < 4; ++kk) {
                bf16x8 hh0 = *(const bf16x8*)&sm.a.hhi[lr     ][kk * 32 + lq * 8];
                bf16x8 hh1 = *(const bf16x8*)&sm.a.hhi[16 + lr][kk * 32 + lq * 8];
                bf16x8 hl0 = *(const bf16x8*)&sm.a.hlo[lr     ][kk * 32 + lq * 8];
                bf16x8 hl1 = *(const bf16x8*)&sm.a.hlo[16 + lr][kk * 32 + lq * 8];
#pragma unroll
                for (int v = 0; v < 4; ++v) {
                    size_t ro = (size_t)v * MATSZ + (size_t)(w * 16 + lr) * BOND + kk * 32 + lq * 8;
                    bf16x8 bh = *(const bf16x8*)(Bh + ro);
                    acc[v][0] = mfma16(bh, hh0, acc[v][0]);
                    acc[v][0] = mfma16(bh, hl0, acc[v][0]);
                    acc[v][1] = mfma16(bh, hh1, acc[v][1]);
                    acc[v][1] = mfma16(bh, hl1, acc[v][1]);
                    if (USE_BLO) {
                        bf16x8 bl = *(const bf16x8*)(Bl + ro);
                        acc[v][0] = mfma16(bl, hh0, acc[v][0]);
                        acc[v][1] = mfma16(bl, hh1, acc[v][1]);
                    }
                }
            }
            __syncthreads();                           // all h LDS reads done
            f32x4 h2[2];
#pragma unroll
            for (int ct = 0; ct < 2; ++ct) {
                int tok = sm.a.toks[t * 32 + ct * 16 + lr];
                f32x4 d = acc[0][ct];
                d = (tok == 1) ? acc[1][ct] : d;
                d = (tok == 2) ? acc[2][ct] : d;
                d = (tok == 3) ? acc[3][ct] : d;
                f32x4 ho = *(const f32x4*)&sm.a.hf[ct * 16 + lr][w * 16 + lq * 4];
                h2[ct] = ho + d;
            }
            if ((t & 7) == 7) {                        // renormalize every 8 steps
#pragma unroll
                for (int ct = 0; ct < 2; ++ct) {
                    float ss = h2[ct][0]*h2[ct][0] + h2[ct][1]*h2[ct][1]
                             + h2[ct][2]*h2[ct][2] + h2[ct][3]*h2[ct][3];
                    ss += __shfl_xor(ss, 16);
                    ss += __shfl_xor(ss, 32);
                    if (lq == 0) sm.a.partial[w][ct * 16 + lr] = ss;
                }
                __syncthreads();
                if (tid < 32) {
                    float s2 = 0.f;
#pragma unroll
                    for (int w2 = 0; w2 < 8; ++w2) s2 += sm.a.partial[w2][tid];
                    sm.a.sinv[tid] = rsqrtf(s2);
                    sm.a.logn[tid] += 0.5f * logf(s2);
                }
                __syncthreads();
#pragma unroll
                for (int ct = 0; ct < 2; ++ct) {
                    float si = sm.a.sinv[ct * 16 + lr];
                    h2[ct] *= si;
                }
            }
#pragma unroll
            for (int ct = 0; ct < 2; ++ct) {
                *(f32x4*)&sm.a.hf[ct * 16 + lr][w * 16 + lq * 4] = h2[ct];
                unsigned short q0 = f2bf(h2[ct][0]), q1 = f2bf(h2[ct][1]),
                               q2 = f2bf(h2[ct][2]), q3 = f2bf(h2[ct][3]);
                *(ushort4*)&sm.a.hhi[ct * 16 + lr][w * 16 + lq * 4] =
                    make_ushort4(q0, q1, q2, q3);
                *(ushort4*)&sm.a.hlo[ct * 16 + lr][w * 16 + lq * 4] =
                    make_ushort4(f2bf(h2[ct][0] - bf2f(q0)), f2bf(h2[ct][1] - bf2f(q1)),
                                 f2bf(h2[ct][2] - bf2f(q2)), f2bf(h2[ct][3] - bf2f(q3)));
            }
            __syncthreads();                           // writes visible before next step's reads
        }
        if (tid < BOND) sm.a.ev[tid] = edge[BOND + tid];  // omega
        __syncthreads();
        if (tid < 32) {
            float dot = 0.f;
            for (int r = 0; r < BOND; ++r) dot += sm.a.hf[tid][r] * sm.a.ev[r];
            logamp[b0 + tid] = 2.f * (logf(fabsf(dot)) + sm.a.logn[tid]);
        }
    }
}

// ---------------- finalize: logZ = log<M_fwd, M_bwd> + 256*log4; out = logamp - logZ ----------------
__global__ __launch_bounds__(1024) void fin_kernel(const unsigned short* __restrict__ mws,
                                                   const float* __restrict__ logamp,
                                                   float* __restrict__ out) {
    __shared__ float red[1024];
    const int tid = threadIdx.x;
    const unsigned short* Sf = mws;
    const unsigned short* Rb = mws + MATSZ;
    float part = 0.f;
    for (int j = 0; j < 16; ++j) {
        int idx = tid + j * 1024;
        part += bf2f(Sf[idx]) * bf2f(Rb[idx]);
    }
    red[tid] = part;
    __syncthreads();
    for (int off = 512; off > 0; off >>= 1) {
        if (tid < off) red[tid] += red[tid + off];
        __syncthreads();
    }
    float lz = logf(red[0]) + 256.0f * 1.3862943611198906f;
    out[tid]        = logamp[tid]        - lz;
    out[tid + 1024] = logamp[tid + 1024] - lz;
}

extern "C" void kernel_launch(void* const* d_in, const int* in_sizes, int n_in,
                              void* d_out, int out_size, void* d_ws, size_t ws_size,
                              hipStream_t stream) {
    const int*   xdata = (const int*)d_in[0];
    const float* core  = (const float*)d_in[1];
    const float* edge  = (const float*)d_in[2];
    float* out = (float*)d_out;
    char* ws = (char*)d_ws;

    const size_t need_full  = OFF_BLO + SZ_MAT + SZ_TAIL;
    const size_t need_noblo = OFF_BLO + SZ_TAIL;
    const int use_blo = (ws_size >= need_full) ? 1 : 0;
    if (!use_blo && ws_size < need_noblo) return;

    unsigned short* abf  = (unsigned short*)(ws + OFF_ABF);
    unsigned short* atbf = (unsigned short*)(ws + OFF_ATBF);
    unsigned short* bhi  = (unsigned short*)(ws + OFF_BHI);
    unsigned short* blo  = (unsigned short*)(ws + (use_blo ? OFF_BLO : OFF_BHI));
    const size_t tail = use_blo ? (OFF_BLO + SZ_MAT) : OFF_BLO;
    unsigned short* mws  = (unsigned short*)(ws + tail);
    float* logamp = (float*)(ws + tail + SZ_MWS);

    convert_kernel<<<SEQ * INP, 256, 0, stream>>>(core, abf, atbf, bhi, blo, use_blo);
    if (use_blo)
        main_kernel<1><<<66, 512, 0, stream>>>(xdata, edge, abf, atbf, bhi, blo, mws, logamp);
    else
        main_kernel<0><<<66, 512, 0, stream>>>(xdata, edge, abf, atbf, bhi, blo, mws, logamp);
    fin_kernel<<<1, 1024, 0, stream>>>(mws, logamp, out);
}

// Round 5
// 2615.841 us; speedup vs baseline: 2.2672x; 2.1914x over previous
//
#include <hip/hip_runtime.h>
#include <cstdint>
#include <cstddef>

#define SEQ   256
#define INP   4
#define BOND  128
#define BATCH 2048
#define MATSZ (BOND*BOND)

typedef __bf16 bf16x8 __attribute__((ext_vector_type(8)));
typedef float  f32x4  __attribute__((ext_vector_type(4)));

// ---- workspace layout (bytes) ----
static constexpr size_t SZ_MAT   = (size_t)SEQ*INP*MATSZ*2;   // 32 MiB each
static constexpr size_t OFF_ABF  = 0;
static constexpr size_t OFF_ATBF = OFF_ABF + SZ_MAT;
static constexpr size_t OFF_BHI  = OFF_ATBF + SZ_MAT;
static constexpr size_t OFF_BLO  = OFF_BHI + SZ_MAT;
static constexpr size_t SZ_MWS   = 2ull*MATSZ*2;              // 2 chains final M (bf16, linear)
static constexpr size_t SZ_TAIL  = SZ_MWS + (size_t)BATCH*4 + 64;

static __device__ __forceinline__ unsigned short f2bf(float f) {
    union { float f; uint32_t u; } v; v.f = f;
    uint32_t r = (v.u + 0x7FFFu + ((v.u >> 16) & 1u)) >> 16;   // RNE
    return (unsigned short)r;
}
static __device__ __forceinline__ float bf2f(unsigned short b) {
    union { uint32_t u; float f; } v; v.u = ((uint32_t)b) << 16;
    return v.f;
}
static __device__ __forceinline__ f32x4 mfma16(bf16x8 a, bf16x8 b, f32x4 c) {
    return __builtin_amdgcn_mfma_f32_16x16x32_bf16(a, b, c, 0, 0, 0);
}
// XOR-swizzled LDS layout: matrix stored as 16B chunks; chunk (r, c8) lives at
// slot r*16 + (c8 ^ (r&15)). Returns SHORT index of chunk start.
static __device__ __forceinline__ int xoff(int r, int c8) {
    return ((r << 4) + (c8 ^ (r & 15))) << 3;
}
// async global->LDS 16B, linear LDS dest (lane*16), pre-swizzled global source
static __device__ __forceinline__ void gload_lds16(const unsigned short* g, unsigned short* l) {
    __builtin_amdgcn_global_load_lds((const __attribute__((address_space(1))) unsigned int*)g,
                                     (__attribute__((address_space(3))) unsigned int*)l,
                                     16, 0, 0);
}
// stage one 128x128 bf16 matrix into XOR-swizzled LDS (all 512 threads)
static __device__ __forceinline__ void stage_mat(const unsigned short* __restrict__ Ai,
                                                 unsigned short* dst, int tid) {
#pragma unroll
    for (int j = 0; j < 4; ++j) {
        int slot = j * 512 + tid;
        int r = slot >> 4, c8 = slot & 15;
        const unsigned short* src = Ai + (size_t)r * BOND + ((c8 ^ (r & 15)) << 3);
        unsigned short* ldst = dst + (size_t)(j * 512 + (tid & ~63)) * 8;
        gload_lds16(src, ldst);
    }
}

// ---------------- convert: fp32 core -> bf16 A, bf16 A^T, bf16 hi/lo of (A - I) ----------------
__global__ void convert_kernel(const float* __restrict__ core,
                               unsigned short* __restrict__ abf,
                               unsigned short* __restrict__ atbf,
                               unsigned short* __restrict__ bhi,
                               unsigned short* __restrict__ blo,
                               int use_blo) {
    __shared__ unsigned short tile[BOND][BOND + 2];
    const int mat = blockIdx.x;                       // 0..1023  (t*4+v)
    const float* src = core + (size_t)mat * MATSZ;
    unsigned short* dA = abf  + (size_t)mat * MATSZ;
    unsigned short* dT = atbf + (size_t)mat * MATSZ;
    unsigned short* dH = bhi  + (size_t)mat * MATSZ;
    unsigned short* dL = blo  + (size_t)mat * MATSZ;
    const int tid = threadIdx.x;
    for (int j = 0; j < 16; ++j) {
        int lin4 = (tid + j * 256) * 4;
        float4 f = *(const float4*)(src + lin4);
        int r = lin4 >> 7, c = lin4 & 127;
        unsigned short a0=f2bf(f.x), a1=f2bf(f.y), a2=f2bf(f.z), a3=f2bf(f.w);
        *(ushort4*)(dA + lin4) = make_ushort4(a0,a1,a2,a3);
        tile[r][c]=a0; tile[r][c+1]=a1; tile[r][c+2]=a2; tile[r][c+3]=a3;
        float b0 = f.x - ((r == c    ) ? 1.0f : 0.0f);
        float b1 = f.y - ((r == c + 1) ? 1.0f : 0.0f);
        float b2 = f.z - ((r == c + 2) ? 1.0f : 0.0f);
        float b3 = f.w - ((r == c + 3) ? 1.0f : 0.0f);
        unsigned short h0=f2bf(b0), h1=f2bf(b1), h2=f2bf(b2), h3=f2bf(b3);
        *(ushort4*)(dH + lin4) = make_ushort4(h0,h1,h2,h3);
        if (use_blo) {
            *(ushort4*)(dL + lin4) = make_ushort4(
                f2bf(b0 - bf2f(h0)), f2bf(b1 - bf2f(h1)),
                f2bf(b2 - bf2f(h2)), f2bf(b3 - bf2f(h3)));
        }
    }
    __syncthreads();
    for (int j = 0; j < 16; ++j) {
        int lin4 = (tid + j * 256) * 4;
        int co = lin4 >> 7, r0 = lin4 & 127;
        *(ushort4*)(dT + lin4) = make_ushort4(tile[r0][co], tile[r0+1][co],
                                              tile[r0+2][co], tile[r0+3][co]);
    }
}

// ---------------- main kernel: blocks 0..1 = Z chains, 2..65 = amplitude ----------------
struct ZSm {
    unsigned short As[2][MATSZ];    // double-buffered A_i, XOR layout (64 KB)
    unsigned short M[MATSZ];        // density matrix, XOR layout (32 KB)
    unsigned short Ti[MATSZ];       // T = A_i * M, XOR layout (32 KB)
    float vec[BOND];
};
struct ASm {
    int   toks[SEQ * 32];           // prefetched tokens (32 KB)
    float hf[32][132];              // fp32 h state [batch-col][dim]
    unsigned short hhi[32 * BOND];  // bf16 hi of h, XOR layout (flat)
    unsigned short hlo[32 * BOND];  // bf16 lo of h, XOR layout (flat)
    float ev[BOND];
    float partial[8][32];
    float sinv[32];
    float logn[32];
};
union SmU { ZSm z; ASm a; };

template<int USE_BLO>
__global__ __launch_bounds__(512) void main_kernel(
        const int*   __restrict__ xdata,
        const float* __restrict__ edge,
        const unsigned short* __restrict__ abf,
        const unsigned short* __restrict__ atbf,
        const unsigned short* __restrict__ bhi,
        const unsigned short* __restrict__ blo,
        unsigned short* __restrict__ mws,
        float* __restrict__ logamp) {
    __shared__ SmU sm;
    const int tid = threadIdx.x;
    const int l   = tid & 63;
    const int w   = tid >> 6;          // wave 0..7
    const int lr  = l & 15;
    const int lq  = l >> 4;

    if (blockIdx.x < 2) {
        // ================= Z chain: one block per chain, LDS-resident =================
        const int chain = blockIdx.x;                  // 0 = fwd (alpha), 1 = bwd (omega, A^T)
        const unsigned short* Abase = chain ? atbf : abf;
        const int rb = w >> 1;                         // row-band 0..3 (32 rows)
        const int ch = w & 1;                          // col-half 0..1 (64 cols)

        if (tid < BOND) sm.z.vec[tid] = edge[chain * BOND + tid];
        __syncthreads();
        // M0 = vec vec^T into XOR layout
        for (int idx = tid; idx < MATSZ; idx += 512) {
            int r = idx >> 7, c = idx & 127;
            sm.z.M[xoff(r, c >> 3) + (c & 7)] = f2bf(sm.z.vec[r] * sm.z.vec[c]);
        }
        // prologue: stage A(s=1, i=0) into As[0]
        {
            const int t0 = chain ? (SEQ - 1) : 0;
            stage_mat(Abase + (size_t)t0 * INP * MATSZ, sm.z.As[0], tid);
        }
        __syncthreads();   // M0 + As[0] ready (barrier drains vmcnt)

        for (int s = 1; s <= 128; ++s) {
            const int tstep = chain ? (SEQ - s) : (s - 1);
            const unsigned short* As_g = Abase + (size_t)tstep * INP * MATSZ;
            f32x4 accM[2][4] = {};
            for (int i = 0; i < 4; ++i) {
                const unsigned short* Acur = sm.z.As[i & 1];
                // ---- phase 1: T[rb-rows][ch-cols] = A_i * M (M symmetric: row-reads) ----
                f32x4 accT[2][4] = {};
#pragma unroll
                for (int kk = 0; kk < 4; ++kk) {
                    bf16x8 af0 = *(const bf16x8*)&Acur[xoff(rb * 32 + lr,      kk * 4 + lq)];
                    bf16x8 af1 = *(const bf16x8*)&Acur[xoff(rb * 32 + 16 + lr, kk * 4 + lq)];
#pragma unroll
                    for (int nt = 0; nt < 4; ++nt) {
                        bf16x8 bm = *(const bf16x8*)&sm.z.M[xoff((ch * 4 + nt) * 16 + lr, kk * 4 + lq)];
                        accT[0][nt] = mfma16(af0, bm, accT[0][nt]);
                        accT[1][nt] = mfma16(af1, bm, accT[1][nt]);
                    }
                }
                __syncthreads();   // B1: all waves done with prev phase-2 (Ti reads, old As buf)
                // stage next matrix into the buffer freed by prev phase-2
                if (i < 3) {
                    stage_mat(As_g + (size_t)(i + 1) * MATSZ, sm.z.As[(i & 1) ^ 1], tid);
                } else if (s < 128) {
                    const int nstep = chain ? (SEQ - s - 1) : s;
                    stage_mat(Abase + (size_t)nstep * INP * MATSZ, sm.z.As[(i & 1) ^ 1], tid);
                }
                // write Ti (XOR layout)
#pragma unroll
                for (int rt = 0; rt < 2; ++rt)
#pragma unroll
                    for (int nt = 0; nt < 4; ++nt)
#pragma unroll
                        for (int r4 = 0; r4 < 4; ++r4) {
                            int row = rb * 32 + rt * 16 + lq * 4 + r4;
                            int col = ch * 64 + nt * 16 + lr;
                            sm.z.Ti[xoff(row, col >> 3) + (col & 7)] = f2bf(accT[rt][nt][r4]);
                        }
                __syncthreads();   // B2: Ti visible + staged As ready (barrier drains vmcnt)
                // ---- phase 2: accM += T * A_i^T  (B[k][n] = A_i[col][k], row-reads) ----
#pragma unroll
                for (int kk = 0; kk < 4; ++kk) {
                    bf16x8 tf0 = *(const bf16x8*)&sm.z.Ti[xoff(rb * 32 + lr,      kk * 4 + lq)];
                    bf16x8 tf1 = *(const bf16x8*)&sm.z.Ti[xoff(rb * 32 + 16 + lr, kk * 4 + lq)];
#pragma unroll
                    for (int nt = 0; nt < 4; ++nt) {
                        bf16x8 ba = *(const bf16x8*)&Acur[xoff(ch * 64 + nt * 16 + lr, kk * 4 + lq)];
                        accM[0][nt] = mfma16(tf0, ba, accM[0][nt]);
                        accM[1][nt] = mfma16(tf1, ba, accM[1][nt]);
                    }
                }
            }
            // write M (scaled 1/4); safe: all phase-1 M reads precede B1(i=3)
#pragma unroll
            for (int rt = 0; rt < 2; ++rt)
#pragma unroll
                for (int nt = 0; nt < 4; ++nt)
#pragma unroll
                    for (int r4 = 0; r4 < 4; ++r4) {
                        int row = rb * 32 + rt * 16 + lq * 4 + r4;
                        int col = ch * 64 + nt * 16 + lr;
                        sm.z.M[xoff(row, col >> 3) + (col & 7)] = f2bf(accM[rt][nt][r4] * 0.25f);
                    }
            __syncthreads();       // B3: M ready for next step
        }
        // publish final M (convert XOR layout -> linear global)
        unsigned short* outb = mws + (size_t)chain * MATSZ;
        for (int j = 0; j < 4; ++j) {
            int chunk = tid + j * 512;                 // 2048 chunks of 8 shorts
            int r = chunk >> 4, c8 = chunk & 15;
            *(bf16x8*)(outb + (size_t)r * BOND + c8 * 8) =
                *(const bf16x8*)&sm.z.M[xoff(r, c8)];
        }
    } else {
        // ================= amplitude scan, delta form: h' = h + B[tok] h =================
        const int b0 = (blockIdx.x - 2) * 32;
        for (int j = 0; j < 16; ++j) {
            int idx = tid + j * 512;                   // 8192 tokens
            int t = idx >> 5, c = idx & 31;
            sm.a.toks[idx] = xdata[(size_t)t * BATCH + b0 + c];
        }
        if (tid < BOND) sm.a.ev[tid] = edge[tid];      // alpha
        if (tid < 32)  sm.a.logn[tid] = 0.f;
        __syncthreads();
        for (int idx = tid; idx < 32 * BOND; idx += 512) {
            int c = idx >> 7, r = idx & 127;
            float v = sm.a.ev[r];
            unsigned short hh = f2bf(v);
            sm.a.hf[c][r] = v;
            int si = xoff(c, r >> 3) + (r & 7);        // FLAT XOR index (bug fix: was hhi[c][...])
            sm.a.hhi[si] = hh;
            sm.a.hlo[si] = f2bf(v - bf2f(hh));
        }
        __syncthreads();

        for (int t = 0; t < SEQ; ++t) {
            const unsigned short* Bh = bhi + (size_t)t * INP * MATSZ;
            const unsigned short* Bl = blo + (size_t)t * INP * MATSZ;
            // ---- bulk-preload all B fragments for this step (independent loads) ----
            bf16x8 bh[4][4], bl[4][4];                 // [kk][v]
#pragma unroll
            for (int kk = 0; kk < 4; ++kk)
#pragma unroll
                for (int v = 0; v < 4; ++v) {
                    size_t ro = (size_t)v * MATSZ + (size_t)(w * 16 + lr) * BOND + kk * 32 + lq * 8;
                    bh[kk][v] = *(const bf16x8*)(Bh + ro);
                    if (USE_BLO) bl[kk][v] = *(const bf16x8*)(Bl + ro);
                }
            f32x4 acc[4][2] = {};                      // [token][col-tile]
#pragma unroll
            for (int kk = 0; kk < 4; ++kk) {
                bf16x8 hh0 = *(const bf16x8*)&sm.a.hhi[xoff(lr,      kk * 4 + lq)];
                bf16x8 hh1 = *(const bf16x8*)&sm.a.hhi[xoff(16 + lr, kk * 4 + lq)];
                bf16x8 hl0 = *(const bf16x8*)&sm.a.hlo[xoff(lr,      kk * 4 + lq)];
                bf16x8 hl1 = *(const bf16x8*)&sm.a.hlo[xoff(16 + lr, kk * 4 + lq)];
#pragma unroll
                for (int v = 0; v < 4; ++v) {
                    acc[v][0] = mfma16(bh[kk][v], hh0, acc[v][0]);
                    acc[v][0] = mfma16(bh[kk][v], hl0, acc[v][0]);
                    acc[v][1] = mfma16(bh[kk][v], hh1, acc[v][1]);
                    acc[v][1] = mfma16(bh[kk][v], hl1, acc[v][1]);
                    if (USE_BLO) {
                        acc[v][0] = mfma16(bl[kk][v], hh0, acc[v][0]);
                        acc[v][1] = mfma16(bl[kk][v], hh1, acc[v][1]);
                    }
                }
            }
            __syncthreads();                           // all h LDS reads done
            f32x4 h2[2];
#pragma unroll
            for (int ct = 0; ct < 2; ++ct) {
                int tok = sm.a.toks[t * 32 + ct * 16 + lr];
                f32x4 d = acc[0][ct];
                d = (tok == 1) ? acc[1][ct] : d;
                d = (tok == 2) ? acc[2][ct] : d;
                d = (tok == 3) ? acc[3][ct] : d;
                f32x4 ho = *(const f32x4*)&sm.a.hf[ct * 16 + lr][w * 16 + lq * 4];
                h2[ct] = ho + d;
            }
            if ((t & 7) == 7) {                        // renormalize every 8 steps
#pragma unroll
                for (int ct = 0; ct < 2; ++ct) {
                    float ss = h2[ct][0]*h2[ct][0] + h2[ct][1]*h2[ct][1]
                             + h2[ct][2]*h2[ct][2] + h2[ct][3]*h2[ct][3];
                    ss += __shfl_xor(ss, 16);
                    ss += __shfl_xor(ss, 32);
                    if (lq == 0) sm.a.partial[w][ct * 16 + lr] = ss;
                }
                __syncthreads();
                if (tid < 32) {
                    float s2 = 0.f;
#pragma unroll
                    for (int w2 = 0; w2 < 8; ++w2) s2 += sm.a.partial[w2][tid];
                    sm.a.sinv[tid] = rsqrtf(s2);
                    sm.a.logn[tid] += 0.5f * logf(s2);
                }
                __syncthreads();
#pragma unroll
                for (int ct = 0; ct < 2; ++ct) h2[ct] *= sm.a.sinv[ct * 16 + lr];
            }
#pragma unroll
            for (int ct = 0; ct < 2; ++ct) {
                int c = ct * 16 + lr;
                *(f32x4*)&sm.a.hf[c][w * 16 + lq * 4] = h2[ct];
                unsigned short q0 = f2bf(h2[ct][0]), q1 = f2bf(h2[ct][1]),
                               q2 = f2bf(h2[ct][2]), q3 = f2bf(h2[ct][3]);
                int c8w = w * 2 + (lq >> 1);
                int si  = xoff(c, c8w) + (lq & 1) * 4;
                *(ushort4*)&sm.a.hhi[si] = make_ushort4(q0, q1, q2, q3);
                *(ushort4*)&sm.a.hlo[si] =
                    make_ushort4(f2bf(h2[ct][0] - bf2f(q0)), f2bf(h2[ct][1] - bf2f(q1)),
                                 f2bf(h2[ct][2] - bf2f(q2)), f2bf(h2[ct][3] - bf2f(q3)));
            }
            __syncthreads();                           // writes visible before next step
        }
        if (tid < BOND) sm.a.ev[tid] = edge[BOND + tid];  // omega
        __syncthreads();
        if (tid < 32) {
            float dot = 0.f;
            for (int r = 0; r < BOND; ++r) dot += sm.a.hf[tid][r] * sm.a.ev[r];
            logamp[b0 + tid] = 2.f * (logf(fabsf(dot)) + sm.a.logn[tid]);
        }
    }
}

// ---------------- finalize: logZ = log<M_fwd, M_bwd> + 256*log4; out = logamp - logZ ----------------
__global__ __launch_bounds__(1024) void fin_kernel(const unsigned short* __restrict__ mws,
                                                   const float* __restrict__ logamp,
                                                   float* __restrict__ out) {
    __shared__ float red[1024];
    const int tid = threadIdx.x;
    const unsigned short* Sf = mws;
    const unsigned short* Rb = mws + MATSZ;
    float part = 0.f;
    for (int j = 0; j < 16; ++j) {
        int idx = tid + j * 1024;
        part += bf2f(Sf[idx]) * bf2f(Rb[idx]);
    }
    red[tid] = part;
    __syncthreads();
    for (int off = 512; off > 0; off >>= 1) {
        if (tid < off) red[tid] += red[tid + off];
        __syncthreads();
    }
    float lz = logf(red[0]) + 256.0f * 1.3862943611198906f;
    out[tid]        = logamp[tid]        - lz;
    out[tid + 1024] = logamp[tid + 1024] - lz;
}

extern "C" void kernel_launch(void* const* d_in, const int* in_sizes, int n_in,
                              void* d_out, int out_size, void* d_ws, size_t ws_size,
                              hipStream_t stream) {
    const int*   xdata = (const int*)d_in[0];
    const float* core  = (const float*)d_in[1];
    const float* edge  = (const float*)d_in[2];
    float* out = (float*)d_out;
    char* ws = (char*)d_ws;

    const size_t need_full  = OFF_BLO + SZ_MAT + SZ_TAIL;
    const size_t need_noblo = OFF_BLO + SZ_TAIL;
    const int use_blo = (ws_size >= need_full) ? 1 : 0;
    if (!use_blo && ws_size < need_noblo) return;

    unsigned short* abf  = (unsigned short*)(ws + OFF_ABF);
    unsigned short* atbf = (unsigned short*)(ws + OFF_ATBF);
    unsigned short* bhi  = (unsigned short*)(ws + OFF_BHI);
    unsigned short* blo  = (unsigned short*)(ws + (use_blo ? OFF_BLO : OFF_BHI));
    const size_t tail = use_blo ? (OFF_BLO + SZ_MAT) : OFF_BLO;
    unsigned short* mws  = (unsigned short*)(ws + tail);
    float* logamp = (float*)(ws + tail + SZ_MWS);

    convert_kernel<<<SEQ * INP, 256, 0, stream>>>(core, abf, atbf, bhi, blo, use_blo);
    if (use_blo)
        main_kernel<1><<<66, 512, 0, stream>>>(xdata, edge, abf, atbf, bhi, blo, mws, logamp);
    else
        main_kernel<0><<<66, 512, 0, stream>>>(xdata, edge, abf, atbf, bhi, blo, mws, logamp);
    fin_kernel<<<1, 1024, 0, stream>>>(mws, logamp, out);
}